// Round 1
// baseline (57228.308 us; speedup 1.0000x reference)
//
#include <hip/hip_runtime.h>

// CRF forward chain on MI355X.
// Math: u^{s+1} = r_s * diag(exp(h_s)) * E * u^s,  E = exp(transitions) (exact zeros
// at the -10000 constraint entries). Answer = C + log(sum_j exp(T[END,j]) u^S_j).
// 4 independent chunks (Perron-Frobenius contraction, 24-step burn-in), 64 blocks
// per chunk, E fragment (256 floats) resident in VGPRs per lane, flag barrier per step.
//
// ws layout (bytes needed ~= 295 KB):
//   float u_bufs [4][2][2048]   @ float idx 0
//   float usave  [4][2048]      @ 16384   (chunk vector at end of burn-in)
//   float ufin   [4][2048]      @ 24576   (chunk vector at chunk end)
//   float pmaxb  [4][2][64]     @ 32768   (per-block max of produced u, per parity)
//   float cbuf   [4]            @ 33284.. (accumulated log-scale per chunk)
//   int   flags  [4][64][32]    @ int idx 65536 (128B-padded per block, poison 0xAA < 0)

#define TSZ   2048
#define NCH   4
#define GBLK  64
#define BURN  24
#define KCH   8
#define START_I 0
#define END_I   1

__global__ __launch_bounds__(256, 1)
void crf_chain(const float* __restrict__ h, const float* __restrict__ tr,
               float* __restrict__ out, float* __restrict__ ws)
{
    const int tid  = threadIdx.x;
    const int lane = tid & 63;
    const int wv   = tid >> 6;
    const int blk  = blockIdx.x;
    const int c    = blk >> 6;          // chunk id 0..3
    const int b    = blk & (GBLK - 1);  // block within chunk group
    const int row_base = b * 32 + wv * 8;

    float* u_bufs = ws;                               // [NCH][2][TSZ]
    float* usave  = ws + NCH * 2 * TSZ;               // [NCH][TSZ]
    float* ufin   = usave + NCH * TSZ;                // [NCH][TSZ]
    float* pmaxb  = ufin + NCH * TSZ;                 // [NCH][2][GBLK]
    float* cbuf   = pmaxb + NCH * 2 * GBLK;           // [NCH]
    int*   flags  = (int*)ws + 65536;                 // [NCH][GBLK][32]

    // ---- one-time: load E fragment into registers. Lane covers cols j = 4*lane + 256*k + m.
    float e[8][KCH][4];
    #pragma unroll
    for (int r = 0; r < 8; ++r) {
        const float* trow = tr + (size_t)(row_base + r) * TSZ + 4 * lane;
        #pragma unroll
        for (int k = 0; k < KCH; ++k) {
            float4 t4 = *(const float4*)(trow + 256 * k);
            e[r][k][0] = __expf(t4.x);
            e[r][k][1] = __expf(t4.y);
            e[r][k][2] = __expf(t4.z);
            e[r][k][3] = __expf(t4.w);
        }
    }

    const int s_keep  = c * 2048;                        // first kept step boundary
    const int s_begin = (c == 0) ? 0 : (s_keep - BURN);  // first processed step
    const int s_end   = s_keep + 2048;                   // chunk end (exclusive step idx)
    const int T_iter  = s_end - s_begin;

    __shared__ float lds_pm[32];

    // ---- init phase: write start vector into parity-0 buffer, flag = 1
    if (tid < 32) {
        int row = b * 32 + tid;
        float v = (c == 0) ? ((row == START_I) ? 1.0f : 0.0f) : 1.0f;
        u_bufs[(c * 2 + 0) * TSZ + row] = v;
    }
    __syncthreads();
    if (tid == 0) {
        __threadfence();
        __hip_atomic_store(&flags[(c * GBLK + b) * 32], 1,
                           __ATOMIC_RELEASE, __HIP_MEMORY_SCOPE_AGENT);
    }
    {
        int fl;
        do {
            __builtin_amdgcn_s_sleep(1);
            fl = __hip_atomic_load(&flags[(c * GBLK + lane) * 32],
                                   __ATOMIC_RELAXED, __HIP_MEMORY_SCOPE_AGENT);
        } while (!__all(fl >= 1));
        __threadfence();
    }

    float Chat = 0.0f;

    for (int t = 0; t < T_iter; ++t) {
        const int s = s_begin + t;                     // consumes h[s], produces u^{s+1}
        const float* u_in  = u_bufs + (c * 2 + (t & 1)) * TSZ;
        float*       u_out = u_bufs + (c * 2 + ((t + 1) & 1)) * TSZ;

        // uniform rescale from previous iteration's per-block maxima (barrier-visible)
        float rnorm = 1.0f, pmv = 1.0f;
        if (t > 0) {
            float pm = pmaxb[(c * 2 + ((t - 1) & 1)) * GBLK + lane];
            #pragma unroll
            for (int d = 1; d < 64; d <<= 1)
                pm = fmaxf(pm, __shfl_xor(pm, d, 64));
            pmv = pm;
            rnorm = 1.0f / pm;
        }

        // ---- GEMV: acc[r] = sum_j E[row_base+r][j] * u[j]  (lane partials)
        float acc[8];
        #pragma unroll
        for (int r = 0; r < 8; ++r) acc[r] = 0.0f;

        const float* up = u_in + 4 * lane;
        #pragma unroll
        for (int k = 0; k < KCH; ++k) {
            float4 u4 = *(const float4*)(up + 256 * k);
            #pragma unroll
            for (int r = 0; r < 8; ++r) {
                acc[r] = fmaf(e[r][k][0], u4.x, acc[r]);
                acc[r] = fmaf(e[r][k][1], u4.y, acc[r]);
                acc[r] = fmaf(e[r][k][2], u4.z, acc[r]);
                acc[r] = fmaf(e[r][k][3], u4.w, acc[r]);
            }
        }

        // ---- multi-row butterfly reduction: 8 rows x 64 lanes -> row q(lane) per lane
        #pragma unroll
        for (int r = 0; r < 4; ++r) {
            float send = (lane & 1) ? acc[r] : acc[r + 4];
            float recv = __shfl_xor(send, 1, 64);
            float keep = (lane & 1) ? acc[r + 4] : acc[r];
            acc[r] = keep + recv;
        }
        #pragma unroll
        for (int r = 0; r < 2; ++r) {
            float send = (lane & 2) ? acc[r] : acc[r + 2];
            float recv = __shfl_xor(send, 2, 64);
            float keep = (lane & 2) ? acc[r + 2] : acc[r];
            acc[r] = keep + recv;
        }
        {
            float send = (lane & 4) ? acc[0] : acc[1];
            float recv = __shfl_xor(send, 4, 64);
            float keep = (lane & 4) ? acc[1] : acc[0];
            acc[0] = keep + recv;
        }
        acc[0] += __shfl_xor(acc[0], 8, 64);
        acc[0] += __shfl_xor(acc[0], 16, 64);
        acc[0] += __shfl_xor(acc[0], 32, 64);

        // accumulate log-scale for kept steps (all lanes redundantly; same value)
        if (t > 0 && (s + 1) > s_keep) Chat += __logf(pmv);

        const int q = ((lane & 1) << 2) | (lane & 2) | ((lane >> 2) & 1);
        const int grow = row_base + q;
        if (lane < 8) {
            float w = __expf(h[(size_t)s * TSZ + grow]);
            float uval = acc[0] * rnorm * w;
            u_out[grow] = uval;
            lds_pm[wv * 8 + q] = uval;
            if (c > 0 && (s + 1) == s_keep) usave[c * TSZ + grow] = uval;
            if ((s + 1) == s_end)           ufin[c * TSZ + grow] = uval;
        }
        if (t == T_iter - 1 && b == 0 && tid == 0) cbuf[c] = Chat;

        __syncthreads();   // lds_pm complete; all block stores happen-before thread 0
        if (tid == 0) {
            float m = 0.0f;
            #pragma unroll
            for (int i = 0; i < 32; ++i) m = fmaxf(m, lds_pm[i]);
            pmaxb[(c * 2 + (t & 1)) * GBLK + b] = m;
            __threadfence();
            __hip_atomic_store(&flags[(c * GBLK + b) * 32], t + 2,
                               __ATOMIC_RELEASE, __HIP_MEMORY_SCOPE_AGENT);
        }
        // group barrier: every wave polls all 64 block flags (incl. own -> covers thread 0)
        {
            const int tgt = t + 2;
            int fl;
            do {
                __builtin_amdgcn_s_sleep(1);
                fl = __hip_atomic_load(&flags[(c * GBLK + lane) * 32],
                                       __ATOMIC_RELAXED, __HIP_MEMORY_SCOPE_AGENT);
            } while (!__all(fl >= tgt));
            __threadfence();
        }
    }

    // ---- finisher: chunk 0 / block 0 / wave 0 stitches chunks and writes the scalar
    if (c == 0 && b == 0 && wv == 0) {
        for (int cc = 1; cc < NCH; ++cc) {
            const int tgt = (2048 + BURN) + 1;   // final flag value of chunks 1..3
            int fl;
            do {
                __builtin_amdgcn_s_sleep(1);
                fl = __hip_atomic_load(&flags[(cc * GBLK + lane) * 32],
                                       __ATOMIC_RELAXED, __HIP_MEMORY_SCOPE_AGENT);
            } while (!__all(fl >= tgt));
        }
        __threadfence();

        // O = total log-offset of last chunk at its start; stitch via log(sum u) matching
        float O = 0.0f;
        for (int cc = 1; cc < NCH; ++cc) {
            float sa = 0.0f, sb = 0.0f;
            for (int j = lane; j < TSZ; j += 64) {
                sa += ufin[(cc - 1) * TSZ + j];
                sb += usave[cc * TSZ + j];
            }
            #pragma unroll
            for (int d = 1; d < 64; d <<= 1) {
                sa += __shfl_xor(sa, d, 64);
                sb += __shfl_xor(sb, d, 64);
            }
            O += cbuf[cc - 1] + __logf(sa) - __logf(sb);
        }
        // terminal: LSE_j(fv^S_j + T[END,j]) = O + C_last + log(sum_j exp(T[END,j]) u^S_j)
        float se = 0.0f;
        for (int j = lane; j < TSZ; j += 64) {
            se += __expf(tr[(size_t)END_I * TSZ + j]) * ufin[(NCH - 1) * TSZ + j];
        }
        #pragma unroll
        for (int d = 1; d < 64; d <<= 1) se += __shfl_xor(se, d, 64);

        float ans = O + cbuf[NCH - 1] + __logf(se);
        if (lane == 0) out[0] = ans;
    }
}

extern "C" void kernel_launch(void* const* d_in, const int* in_sizes, int n_in,
                              void* d_out, int out_size, void* d_ws, size_t ws_size,
                              hipStream_t stream) {
    const float* h  = (const float*)d_in[0];   // [8192, 2048] fp32 emissions
    const float* tr = (const float*)d_in[1];   // [2048, 2048] fp32 transitions
    (void)in_sizes; (void)n_in; (void)out_size; (void)ws_size;
    crf_chain<<<dim3(NCH * GBLK), dim3(256), 0, stream>>>(h, tr, (float*)d_out, (float*)d_ws);
}

// Round 2
// 29770.605 us; speedup vs baseline: 1.9223x; 1.9223x over previous
//
#include <hip/hip_runtime.h>

// CRF forward chain on MI355X — linearized: u^{s+1} = (1/g_s) diag(exp(h_s)) E u^s,
// E = exp(transitions); answer = C + log(sum_j exp(T[END,j]) u_j).
// 4 chunks (Perron-Frobenius contraction, 24-step burn-in), 64 blocks/chunk,
// E fragment (256 floats) register-resident per lane.
//
// R1 barrier rework: one 8B post per block = (step<<32)|bits(block_max), 64 posts
// per chunk on 4 cache lines, parity-double-buffered so the carried max can't be
// overwritten before all peers have read it. Acquire fence (L2 inv) after poll,
// release fence (L2 wb) + post by tid0 after __syncthreads. One barrier/step.
//
// ws layout (floats): u_bufs[4][2][2048] @0, usave[4][2048] @16384,
// ufin[4][2048] @24576, cbuf[4] @32768 ; posts ull[2][4][64] @byte 262144.

#define TSZ   2048
#define NCH   4
#define GBLK  64
#define BURN  24
#define KCH   8
#define START_I 0
#define END_I   1

__global__ __launch_bounds__(256, 1)
void crf_chain(const float* __restrict__ h, const float* __restrict__ tr,
               float* __restrict__ out, float* __restrict__ ws)
{
    const int tid  = threadIdx.x;
    const int lane = tid & 63;
    const int wv   = tid >> 6;
    const int blk  = blockIdx.x;
    const int c    = blk >> 6;          // chunk id 0..3
    const int b    = blk & (GBLK - 1);  // block within chunk
    const int row_base = b * 32 + wv * 8;

    float* u_bufs = ws;                               // [NCH][2][TSZ]
    float* usave  = ws + NCH * 2 * TSZ;               // [NCH][TSZ]
    float* ufin   = usave + NCH * TSZ;                // [NCH][TSZ]
    float* cbuf   = ufin + NCH * TSZ;                 // [NCH]
    unsigned long long* posts =
        (unsigned long long*)((char*)ws + 262144);    // [2][NCH][GBLK]

    // ---- one-time: E fragment into registers. Lane covers cols j = 4*lane + 256*k + m.
    float e[8][KCH][4];
    #pragma unroll
    for (int r = 0; r < 8; ++r) {
        const float* trow = tr + (size_t)(row_base + r) * TSZ + 4 * lane;
        #pragma unroll
        for (int k = 0; k < KCH; ++k) {
            float4 t4 = *(const float4*)(trow + 256 * k);
            e[r][k][0] = __expf(t4.x);
            e[r][k][1] = __expf(t4.y);
            e[r][k][2] = __expf(t4.z);
            e[r][k][3] = __expf(t4.w);
        }
    }

    const int s_keep  = c * 2048;
    const int s_begin = (c == 0) ? 0 : (s_keep - BURN);
    const int s_end   = s_keep + 2048;
    const int T_iter  = s_end - s_begin;

    __shared__ float lds_wmax[4];

    const int q    = ((lane & 1) << 2) | (lane & 2) | ((lane >> 2) & 1);
    const int grow = row_base + q;

    // ---- init: start vector into parity-0 u buffer; post (1, max=1.0) into parity-0 slot
    if (tid < 32) {
        int row = b * 32 + tid;
        float v = (c == 0) ? ((row == START_I) ? 1.0f : 0.0f) : 1.0f;
        u_bufs[(c * 2 + 0) * TSZ + row] = v;
    }
    __syncthreads();
    if (tid == 0) {
        __builtin_amdgcn_fence(__ATOMIC_RELEASE, "agent");
        __hip_atomic_store(&posts[(0 * NCH + c) * GBLK + b],
                           (1ull << 32) | (unsigned long long)__float_as_uint(1.0f),
                           __ATOMIC_RELAXED, __HIP_MEMORY_SCOPE_AGENT);
    }

    float Chat = 0.0f;

    for (int t = 0; t < T_iter; ++t) {
        const int s = s_begin + t;
        const float* u_in  = u_bufs + (c * 2 + (t & 1)) * TSZ;
        float*       u_out = u_bufs + (c * 2 + ((t + 1) & 1)) * TSZ;

        // prefetch emission factor for this step (h is immutable -> safe pre-fence)
        float wexp = 0.0f;
        if (lane < 8) wexp = __expf(h[(size_t)s * TSZ + grow]);

        // ---- poll: all 64 posts of own chunk, parity t&1, expect step tag >= t+1.
        // Post in parity p is rewritten only 2 steps later, and that rewrite requires
        // our own block's post (after __syncthreads) -> carried max is read-stable.
        float gmax;
        {
            const int tgt = t + 1;
            unsigned long long v;
            int st;
            do {
                __builtin_amdgcn_s_sleep(1);
                v  = __hip_atomic_load(&posts[((t & 1) * NCH + c) * GBLK + lane],
                                       __ATOMIC_RELAXED, __HIP_MEMORY_SCOPE_AGENT);
                st = (int)(v >> 32);
            } while (!__all(st >= tgt));
            float mx = __uint_as_float((unsigned)v);
            #pragma unroll
            for (int d = 1; d < 64; d <<= 1) mx = fmaxf(mx, __shfl_xor(mx, d, 64));
            gmax = mx;
            __builtin_amdgcn_fence(__ATOMIC_ACQUIRE, "agent");  // L2 inv -> fresh u
        }
        const float rnorm = 1.0f / gmax;

        // ---- GEMV: acc[r] = sum_j E[row_base+r][j] * u[j]
        float acc[8];
        #pragma unroll
        for (int r = 0; r < 8; ++r) acc[r] = 0.0f;

        const float* up = u_in + 4 * lane;
        #pragma unroll
        for (int k = 0; k < KCH; ++k) {
            float4 u4 = *(const float4*)(up + 256 * k);
            #pragma unroll
            for (int r = 0; r < 8; ++r) {
                acc[r] = fmaf(e[r][k][0], u4.x, acc[r]);
                acc[r] = fmaf(e[r][k][1], u4.y, acc[r]);
                acc[r] = fmaf(e[r][k][2], u4.z, acc[r]);
                acc[r] = fmaf(e[r][k][3], u4.w, acc[r]);
            }
        }

        // ---- multi-row butterfly reduction: 8 rows x 64 lanes -> row q(lane), lanes 0..7
        #pragma unroll
        for (int r = 0; r < 4; ++r) {
            float send = (lane & 1) ? acc[r] : acc[r + 4];
            float recv = __shfl_xor(send, 1, 64);
            float keep = (lane & 1) ? acc[r + 4] : acc[r];
            acc[r] = keep + recv;
        }
        #pragma unroll
        for (int r = 0; r < 2; ++r) {
            float send = (lane & 2) ? acc[r] : acc[r + 2];
            float recv = __shfl_xor(send, 2, 64);
            float keep = (lane & 2) ? acc[r + 2] : acc[r];
            acc[r] = keep + recv;
        }
        {
            float send = (lane & 4) ? acc[0] : acc[1];
            float recv = __shfl_xor(send, 4, 64);
            float keep = (lane & 4) ? acc[1] : acc[0];
            acc[0] = keep + recv;
        }
        acc[0] += __shfl_xor(acc[0], 8, 64);
        acc[0] += __shfl_xor(acc[0], 16, 64);
        acc[0] += __shfl_xor(acc[0], 32, 64);

        // log-scale accumulation for kept steps (gmax==1.0 exactly at t==0 -> log 0)
        if ((s + 1) > s_keep) Chat += __logf(gmax);

        float wmax = 0.0f;
        if (lane < 8) {
            float uval = acc[0] * rnorm * wexp;
            u_out[grow] = uval;
            wmax = uval;
            if (c > 0 && (s + 1) == s_keep) usave[c * TSZ + grow] = uval;
            if ((s + 1) == s_end)           ufin[c * TSZ + grow] = uval;
        }
        // wave max over lanes 0..7 (u >= 0, inactive lanes contribute 0)
        wmax = fmaxf(wmax, __shfl_xor(wmax, 1, 64));
        wmax = fmaxf(wmax, __shfl_xor(wmax, 2, 64));
        wmax = fmaxf(wmax, __shfl_xor(wmax, 4, 64));
        if (lane == 0) lds_wmax[wv] = wmax;

        if (t == T_iter - 1 && b == 0 && tid == 0) cbuf[c] = Chat;

        __syncthreads();   // all block stores vmcnt-complete (in local L2); lds_wmax ready
        if (tid == 0) {
            float bm = fmaxf(fmaxf(lds_wmax[0], lds_wmax[1]),
                             fmaxf(lds_wmax[2], lds_wmax[3]));
            __builtin_amdgcn_fence(__ATOMIC_RELEASE, "agent");  // flush block's dirty L2
            __hip_atomic_store(&posts[(((t + 1) & 1) * NCH + c) * GBLK + b],
                               ((unsigned long long)(t + 2) << 32) |
                               (unsigned long long)__float_as_uint(bm),
                               __ATOMIC_RELAXED, __HIP_MEMORY_SCOPE_AGENT);
        }
    }

    // ---- finisher: chunk 0 / block 0 / wave 0 stitches chunks, writes scalar
    if (c == 0 && b == 0 && wv == 0) {
        // chunks 1..3: T_iter = 2048+BURN = 2072 -> final post value 2073, parity (2072)&1 = 0
        for (int cc = 1; cc < NCH; ++cc) {
            const int tgt = 2048 + BURN + 1;
            unsigned long long v;
            int st;
            do {
                __builtin_amdgcn_s_sleep(1);
                v  = __hip_atomic_load(&posts[(0 * NCH + cc) * GBLK + lane],
                                       __ATOMIC_RELAXED, __HIP_MEMORY_SCOPE_AGENT);
                st = (int)(v >> 32);
            } while (!__all(st >= tgt));
        }
        __builtin_amdgcn_fence(__ATOMIC_ACQUIRE, "agent");

        // stitch: match log(sum u) at chunk boundaries
        float O = 0.0f;
        for (int cc = 1; cc < NCH; ++cc) {
            float sa = 0.0f, sb = 0.0f;
            for (int j = lane; j < TSZ; j += 64) {
                sa += ufin[(cc - 1) * TSZ + j];
                sb += usave[cc * TSZ + j];
            }
            #pragma unroll
            for (int d = 1; d < 64; d <<= 1) {
                sa += __shfl_xor(sa, d, 64);
                sb += __shfl_xor(sb, d, 64);
            }
            O += cbuf[cc - 1] + __logf(sa) - __logf(sb);
        }
        // terminal: O + C_last + log(sum_j exp(T[END,j]) u_j)
        float se = 0.0f;
        for (int j = lane; j < TSZ; j += 64) {
            se += __expf(tr[(size_t)END_I * TSZ + j]) * ufin[(NCH - 1) * TSZ + j];
        }
        #pragma unroll
        for (int d = 1; d < 64; d <<= 1) se += __shfl_xor(se, d, 64);

        float ans = O + cbuf[NCH - 1] + __logf(se);
        if (lane == 0) out[0] = ans;
    }
}

extern "C" void kernel_launch(void* const* d_in, const int* in_sizes, int n_in,
                              void* d_out, int out_size, void* d_ws, size_t ws_size,
                              hipStream_t stream) {
    const float* h  = (const float*)d_in[0];   // [8192, 2048] fp32 emissions
    const float* tr = (const float*)d_in[1];   // [2048, 2048] fp32 transitions
    (void)in_sizes; (void)n_in; (void)out_size; (void)ws_size;
    crf_chain<<<dim3(NCH * GBLK), dim3(256), 0, stream>>>(h, tr, (float*)d_out, (float*)d_ws);
}

// Round 3
// 6055.262 us; speedup vs baseline: 9.4510x; 4.9165x over previous
//
#include <hip/hip_runtime.h>

// CRF forward chain on MI355X — linearized: u^{s+1} = (1/g_s) diag(exp(h_s)) E u^s,
// E = exp(transitions); answer = C + log(sum_j exp(T[END,j]) u_j).
// 4 chunks (Perron-Frobenius contraction, BURN-step burn-in), 64 blocks/chunk,
// E fragment (256 floats) register-resident per lane.
//
// R3: ZERO cache-wide fences. All cross-block data moves through sc0/sc1-flagged
// (cache-bypassing, write-through-to-L3) loads/stores; ordering is vmcnt-based:
// stores acked at coherence point before the 8B post; consumers poll posts
// (relaxed agent atomics) with wave 0 only + LDS broadcast, then batched
// dwordx4 sc0 sc1 loads of u. No buffer_inv / buffer_wbl2 anywhere.
//
// ws layout (floats): u_bufs[4][2][2048] @0, usave[4][2048] @16384,
// ufin[4][2048] @24576, cbuf[4] @32768 ; posts ull[2][4][64] @byte 262144.

#define TSZ   2048
#define NCH   4
#define GBLK  64
#define BURN  24
#define KCH   8
#define START_I 0
#define END_I   1

typedef float v4f __attribute__((ext_vector_type(4)));

__device__ __forceinline__ void st_coh(float* p, float v) {
    asm volatile("global_store_dword %0, %1, off sc0 sc1"
                 :: "v"(p), "v"(v) : "memory");
}
__device__ __forceinline__ v4f ld_coh4(const float* p) {
    v4f r;
    asm volatile("global_load_dwordx4 %0, %1, off sc0 sc1\n\ts_waitcnt vmcnt(0)"
                 : "=&v"(r) : "v"(p) : "memory");
    return r;
}

__global__ __launch_bounds__(256, 1)
void crf_chain(const float* __restrict__ h, const float* __restrict__ tr,
               float* __restrict__ out, float* __restrict__ ws)
{
    const int tid  = threadIdx.x;
    const int lane = tid & 63;
    const int wv   = tid >> 6;
    const int blk  = blockIdx.x;
    const int c    = blk >> 6;          // chunk id 0..3
    const int b    = blk & (GBLK - 1);  // block within chunk
    const int row_base = b * 32 + wv * 8;

    float* u_bufs = ws;                               // [NCH][2][TSZ]
    float* usave  = ws + NCH * 2 * TSZ;               // [NCH][TSZ]
    float* ufin   = usave + NCH * TSZ;                // [NCH][TSZ]
    float* cbuf   = ufin + NCH * TSZ;                 // [NCH]
    unsigned long long* posts =
        (unsigned long long*)((char*)ws + 262144);    // [2][NCH][GBLK]

    // ---- one-time: E fragment into registers. Lane covers cols j = 4*lane + 256*k + m.
    float e[8][KCH][4];
    #pragma unroll
    for (int r = 0; r < 8; ++r) {
        const float* trow = tr + (size_t)(row_base + r) * TSZ + 4 * lane;
        #pragma unroll
        for (int k = 0; k < KCH; ++k) {
            float4 t4 = *(const float4*)(trow + 256 * k);
            e[r][k][0] = __expf(t4.x);
            e[r][k][1] = __expf(t4.y);
            e[r][k][2] = __expf(t4.z);
            e[r][k][3] = __expf(t4.w);
        }
    }

    const int s_keep  = c * 2048;
    const int s_begin = (c == 0) ? 0 : (s_keep - BURN);
    const int s_end   = s_keep + 2048;
    const int T_iter  = s_end - s_begin;

    __shared__ float lds_wmax[4];
    __shared__ float lds_g;

    const int q    = ((lane & 1) << 2) | (lane & 2) | ((lane >> 2) & 1);
    const int grow = row_base + q;

    // ---- init: start vector into parity-0 u buffer (coherent stores), post tag 1
    if (tid < 32) {
        int row = b * 32 + tid;
        float v = (c == 0) ? ((row == START_I) ? 1.0f : 0.0f) : 1.0f;
        st_coh(&u_bufs[(c * 2 + 0) * TSZ + row], v);
    }
    asm volatile("s_waitcnt vmcnt(0)" ::: "memory");
    __syncthreads();
    if (tid == 0) {
        __hip_atomic_store(&posts[(0 * NCH + c) * GBLK + b],
                           (1ull << 32) | (unsigned long long)__float_as_uint(1.0f),
                           __ATOMIC_RELAXED, __HIP_MEMORY_SCOPE_AGENT);
    }

    float Chat = 0.0f;

    for (int t = 0; t < T_iter; ++t) {
        const int s = s_begin + t;
        const float* u_in  = u_bufs + (c * 2 + (t & 1)) * TSZ;
        float*       u_out = u_bufs + (c * 2 + ((t + 1) & 1)) * TSZ;

        // prefetch emission (plain cached load; h is read-only) to overlap the wait
        float hv = 0.0f;
        if (lane < 8) hv = h[(size_t)s * TSZ + grow];

        // ---- wave 0 polls all 64 posts of own chunk, parity t&1, tag >= t+1.
        // Parity slot is rewritten only 2 steps later, and that rewrite requires our
        // own post (post-__syncthreads) -> carried max is read-stable. LDS-broadcast.
        if (wv == 0) {
            const int tgt = t + 1;
            unsigned long long v;
            int st;
            do {
                __builtin_amdgcn_s_sleep(1);
                v  = __hip_atomic_load(&posts[((t & 1) * NCH + c) * GBLK + lane],
                                       __ATOMIC_RELAXED, __HIP_MEMORY_SCOPE_AGENT);
                st = (int)(v >> 32);
            } while (!__all(st >= tgt));
            float mx = __uint_as_float((unsigned)v);
            #pragma unroll
            for (int d = 1; d < 64; d <<= 1) mx = fmaxf(mx, __shfl_xor(mx, d, 64));
            if (lane == 0) lds_g = mx;
        }
        __syncthreads();                 // orders poll-success before u loads, broadcasts gmax
        const float gmax  = lds_g;
        const float rnorm = 1.0f / gmax;

        // ---- batched coherent load of the full u vector slice for this lane:
        // u[4*lane + 256*k + m], k=0..7 -> two bases, 4 x 1024B offsets each, one vmcnt.
        v4f u0, u1, u2, u3, u4, u5, u6, u7;
        {
            const float* pa = u_in + 4 * lane;       // k=0..3
            const float* pb = pa + 1024;             // k=4..7
            asm volatile(
                "global_load_dwordx4 %0, %8, off sc0 sc1\n\t"
                "global_load_dwordx4 %1, %8, off offset:1024 sc0 sc1\n\t"
                "global_load_dwordx4 %2, %8, off offset:2048 sc0 sc1\n\t"
                "global_load_dwordx4 %3, %8, off offset:3072 sc0 sc1\n\t"
                "global_load_dwordx4 %4, %9, off sc0 sc1\n\t"
                "global_load_dwordx4 %5, %9, off offset:1024 sc0 sc1\n\t"
                "global_load_dwordx4 %6, %9, off offset:2048 sc0 sc1\n\t"
                "global_load_dwordx4 %7, %9, off offset:3072 sc0 sc1\n\t"
                "s_waitcnt vmcnt(0)"
                : "=&v"(u0), "=&v"(u1), "=&v"(u2), "=&v"(u3),
                  "=&v"(u4), "=&v"(u5), "=&v"(u6), "=&v"(u7)
                : "v"(pa), "v"(pb)
                : "memory");
        }

        // ---- GEMV: acc[r] = sum_j E[row_base+r][j] * u[j]
        float acc[8];
        #pragma unroll
        for (int r = 0; r < 8; ++r) acc[r] = 0.0f;
        {
            const v4f uv[8] = {u0, u1, u2, u3, u4, u5, u6, u7};
            #pragma unroll
            for (int k = 0; k < KCH; ++k) {
                #pragma unroll
                for (int r = 0; r < 8; ++r) {
                    acc[r] = fmaf(e[r][k][0], uv[k].x, acc[r]);
                    acc[r] = fmaf(e[r][k][1], uv[k].y, acc[r]);
                    acc[r] = fmaf(e[r][k][2], uv[k].z, acc[r]);
                    acc[r] = fmaf(e[r][k][3], uv[k].w, acc[r]);
                }
            }
        }

        // ---- multi-row butterfly: 8 rows x 64 lanes -> row q(lane), result in lanes 0..7
        #pragma unroll
        for (int r = 0; r < 4; ++r) {
            float send = (lane & 1) ? acc[r] : acc[r + 4];
            float recv = __shfl_xor(send, 1, 64);
            float keep = (lane & 1) ? acc[r + 4] : acc[r];
            acc[r] = keep + recv;
        }
        #pragma unroll
        for (int r = 0; r < 2; ++r) {
            float send = (lane & 2) ? acc[r] : acc[r + 2];
            float recv = __shfl_xor(send, 2, 64);
            float keep = (lane & 2) ? acc[r + 2] : acc[r];
            acc[r] = keep + recv;
        }
        {
            float send = (lane & 4) ? acc[0] : acc[1];
            float recv = __shfl_xor(send, 4, 64);
            float keep = (lane & 4) ? acc[1] : acc[0];
            acc[0] = keep + recv;
        }
        acc[0] += __shfl_xor(acc[0], 8, 64);
        acc[0] += __shfl_xor(acc[0], 16, 64);
        acc[0] += __shfl_xor(acc[0], 32, 64);

        // log-scale accumulation for kept steps (gmax==1.0 at t==0 -> adds 0)
        if ((s + 1) > s_keep) Chat += __logf(gmax);

        float wmax = 0.0f;
        if (lane < 8) {
            float uval = acc[0] * rnorm * __expf(hv);
            st_coh(&u_out[grow], uval);
            wmax = uval;
            if (c > 0 && (s + 1) == s_keep) st_coh(&usave[c * TSZ + grow], uval);
            if ((s + 1) == s_end)           st_coh(&ufin[c * TSZ + grow], uval);
        }
        // wave max over lanes 0..7 (u >= 0; inactive lanes contribute 0)
        wmax = fmaxf(wmax, __shfl_xor(wmax, 1, 64));
        wmax = fmaxf(wmax, __shfl_xor(wmax, 2, 64));
        wmax = fmaxf(wmax, __shfl_xor(wmax, 4, 64));
        if (lane == 0) lds_wmax[wv] = wmax;

        if (t == T_iter - 1 && b == 0 && tid == 0) st_coh(&cbuf[c], Chat);

        asm volatile("s_waitcnt vmcnt(0)" ::: "memory");  // sc stores acked at L3
        __syncthreads();                                  // + lds_wmax ready
        if (tid == 0) {
            float bm = fmaxf(fmaxf(lds_wmax[0], lds_wmax[1]),
                             fmaxf(lds_wmax[2], lds_wmax[3]));
            __hip_atomic_store(&posts[(((t + 1) & 1) * NCH + c) * GBLK + b],
                               ((unsigned long long)(t + 2) << 32) |
                               (unsigned long long)__float_as_uint(bm),
                               __ATOMIC_RELAXED, __HIP_MEMORY_SCOPE_AGENT);
        }
    }

    // ---- finisher: chunk 0 / block 0 / wave 0 stitches chunks, writes scalar
    if (c == 0 && b == 0 && wv == 0) {
        // final post tag = T_iter+1; parity (T_iter-1+1)&1 == 0 for all chunks
        for (int cc = 0; cc < NCH; ++cc) {
            const int tgt = ((cc == 0) ? 2048 : (2048 + BURN)) + 1;
            unsigned long long v;
            int st;
            do {
                __builtin_amdgcn_s_sleep(1);
                v  = __hip_atomic_load(&posts[(0 * NCH + cc) * GBLK + lane],
                                       __ATOMIC_RELAXED, __HIP_MEMORY_SCOPE_AGENT);
                st = (int)(v >> 32);
            } while (!__all(st >= tgt));
        }
        asm volatile("" ::: "memory");

        // stitch: match log(sum u) at chunk boundaries
        float O = 0.0f;
        for (int cc = 1; cc < NCH; ++cc) {
            float sa = 0.0f, sb = 0.0f;
            for (int j = 4 * lane; j < TSZ; j += 256) {
                v4f a4 = ld_coh4(&ufin[(cc - 1) * TSZ + j]);
                v4f b4 = ld_coh4(&usave[cc * TSZ + j]);
                sa += a4.x + a4.y + a4.z + a4.w;
                sb += b4.x + b4.y + b4.z + b4.w;
            }
            #pragma unroll
            for (int d = 1; d < 64; d <<= 1) {
                sa += __shfl_xor(sa, d, 64);
                sb += __shfl_xor(sb, d, 64);
            }
            v4f c4 = ld_coh4(&cbuf[0]);   // cbuf[0..3] in one line; take [cc-1]
            float cv = (cc - 1 == 0) ? c4.x : (cc - 1 == 1) ? c4.y : c4.z;
            O += cv + __logf(sa) - __logf(sb);
        }
        // terminal: O + C_last + log(sum_j exp(T[END,j]) u_j)
        float se = 0.0f;
        for (int j = 4 * lane; j < TSZ; j += 256) {
            const float4 t4 = *(const float4*)(tr + (size_t)END_I * TSZ + j);
            v4f uf = ld_coh4(&ufin[(NCH - 1) * TSZ + j]);
            se += __expf(t4.x) * uf.x + __expf(t4.y) * uf.y +
                  __expf(t4.z) * uf.z + __expf(t4.w) * uf.w;
        }
        #pragma unroll
        for (int d = 1; d < 64; d <<= 1) se += __shfl_xor(se, d, 64);

        v4f c4 = ld_coh4(&cbuf[0]);
        float ans = O + c4.w + __logf(se);
        if (lane == 0) out[0] = ans;
    }
}

extern "C" void kernel_launch(void* const* d_in, const int* in_sizes, int n_in,
                              void* d_out, int out_size, void* d_ws, size_t ws_size,
                              hipStream_t stream) {
    const float* h  = (const float*)d_in[0];   // [8192, 2048] fp32 emissions
    const float* tr = (const float*)d_in[1];   // [2048, 2048] fp32 transitions
    (void)in_sizes; (void)n_in; (void)out_size; (void)ws_size;
    crf_chain<<<dim3(NCH * GBLK), dim3(256), 0, stream>>>(h, tr, (float*)d_out, (float*)d_ws);
}

// Round 5
// 4701.335 us; speedup vs baseline: 12.1728x; 1.2880x over previous
//
#include <hip/hip_runtime.h>

// CRF forward chain on MI355X — linearized: u' = (1/g) diag(exp(h_s)) E u,
// E = exp(transitions) packed as f16 pairs (register-resident, 128 VGPR/lane).
// answer = C + log(sum_j exp(T[END,j]) u_j). 4 chunks (Perron-Frobenius
// contraction, BURN-step burn-in), 64 blocks/chunk.
//
// R4: DATAFLOW SYNC. No posts, no acks, no __syncthreads in the loop.
// Producers store u sign-tagged by buffer-reuse parity (buffer q rewritten
// every 2 steps with alternating sign; -0.0f preserves tag). Consumers poll by
// re-loading the u vector until all 2048 values carry the expected sign — the
// poll IS the load. 2-buffer dataflow chain bounds skew < 2 steps, so tags are
// unambiguous; ws 0xAA poison is sign-negative = "stale" for initial reads.
// gmax computed locally from loaded values (bitwise-identical in every wave).
//
// ws floats: u_bufs[4][2][2048] @0, usave[4][2048] @16384, ufin[4][2048] @24576,
// cbuf[4] @32768 ; completion posts int[1024] @byte 262144.

#define TSZ   2048
#define NCH   4
#define GBLK  64
#define BURN  24
#define START_I 0
#define END_I   1

typedef float v4f __attribute__((ext_vector_type(4)));
typedef _Float16 h2f __attribute__((ext_vector_type(2)));

__device__ __forceinline__ h2f pk16(float a, float b) {
    return __builtin_bit_cast(h2f, __builtin_amdgcn_cvt_pkrtz(a, b));
}

__device__ __forceinline__ void st_coh(float* p, float v) {
    asm volatile("global_store_dword %0, %1, off sc0 sc1"
                 :: "v"(p), "v"(v) : "memory");
}
__device__ __forceinline__ v4f ld_coh4(const float* p) {
    v4f r;
    asm volatile("global_load_dwordx4 %0, %1, off sc0 sc1\n\ts_waitcnt vmcnt(0)"
                 : "=&v"(r) : "v"(p) : "memory");
    return r;
}

__global__ __launch_bounds__(256, 1)
void crf_chain(const float* __restrict__ h, const float* __restrict__ tr,
               float* __restrict__ out, float* __restrict__ ws)
{
    const int tid  = threadIdx.x;
    const int lane = tid & 63;
    const int wv   = tid >> 6;
    const int blk  = blockIdx.x;
    const int c    = blk >> 6;          // chunk id 0..3
    const int b    = blk & (GBLK - 1);  // block within chunk
    const int row_base = b * 32 + wv * 8;

    float* u_bufs = ws;                               // [NCH][2][TSZ]
    float* usave  = ws + NCH * 2 * TSZ;               // [NCH][TSZ]
    float* ufin   = usave + NCH * TSZ;                // [NCH][TSZ]
    float* cbuf   = ufin + NCH * TSZ;                 // [NCH]
    int*   posts  = (int*)ws + 65536;                 // [1024] per-wave completion

    // ---- one-time: E fragment, f16-pair packed. Lane covers cols 4*lane + 256*k + m.
    h2f e2[8][16];
    #pragma unroll
    for (int r = 0; r < 8; ++r) {
        const float* trow = tr + (size_t)(row_base + r) * TSZ + 4 * lane;
        #pragma unroll
        for (int k = 0; k < 8; ++k) {
            float4 t4 = *(const float4*)(trow + 256 * k);
            e2[r][2 * k]     = pk16(__expf(t4.x), __expf(t4.y));
            e2[r][2 * k + 1] = pk16(__expf(t4.z), __expf(t4.w));
        }
    }

    const int s_keep  = c * 2048;
    const int s_begin = (c == 0) ? 0 : (s_keep - BURN);
    const int s_end   = s_keep + 2048;
    const int T_iter  = s_end - s_begin;

    const int q    = ((lane & 1) << 2) | (lane & 2) | ((lane >> 2) & 1);
    const int grow = row_base + q;

    // ---- init: u^0 into buf parity 0, POSITIVE tag (poison 0xAA.. is negative)
    if (tid < 32) {
        int row = b * 32 + tid;
        float v = (c == 0) ? ((row == START_I) ? 1.0f : 0.0f) : 1.0f;
        st_coh(&u_bufs[(c * 2 + 0) * TSZ + row], v);
    }

    float Chat = 0.0f;

    for (int t = 0; t < T_iter; ++t) {
        const int s = s_begin + t;
        const float* u_in  = u_bufs + (c * 2 + (t & 1)) * TSZ;
        float*       u_out = u_bufs + (c * 2 + ((t + 1) & 1)) * TSZ;
        const int in_neg  = (t >> 1) & 1;          // expected tag of u_in
        const int out_neg = ((t + 1) >> 1) & 1;    // tag we write

        // prefetch emission (plain cached load) to overlap the wait
        float hv = 0.0f;
        if (lane < 8) hv = h[(size_t)s * TSZ + grow];

        // ---- poll-by-load: re-load until every value carries the expected sign
        v4f u0, u1, u2, u3, u4, u5, u6, u7;
        const float* pa = u_in + 4 * lane;       // k=0..3
        const float* pb = pa + 1024;             // k=4..7
        for (;;) {
            asm volatile(
                "global_load_dwordx4 %0, %8, off sc0 sc1\n\t"
                "global_load_dwordx4 %1, %8, off offset:1024 sc0 sc1\n\t"
                "global_load_dwordx4 %2, %8, off offset:2048 sc0 sc1\n\t"
                "global_load_dwordx4 %3, %8, off offset:3072 sc0 sc1\n\t"
                "global_load_dwordx4 %4, %9, off sc0 sc1\n\t"
                "global_load_dwordx4 %5, %9, off offset:1024 sc0 sc1\n\t"
                "global_load_dwordx4 %6, %9, off offset:2048 sc0 sc1\n\t"
                "global_load_dwordx4 %7, %9, off offset:3072 sc0 sc1\n\t"
                "s_waitcnt vmcnt(0)"
                : "=&v"(u0), "=&v"(u1), "=&v"(u2), "=&v"(u3),
                  "=&v"(u4), "=&v"(u5), "=&v"(u6), "=&v"(u7)
                : "v"(pa), "v"(pb)
                : "memory");
            bool fresh;
            if (in_neg) {
                int a = __float_as_int(u0.x) & __float_as_int(u0.y) & __float_as_int(u0.z) & __float_as_int(u0.w);
                a &= __float_as_int(u1.x) & __float_as_int(u1.y) & __float_as_int(u1.z) & __float_as_int(u1.w);
                a &= __float_as_int(u2.x) & __float_as_int(u2.y) & __float_as_int(u2.z) & __float_as_int(u2.w);
                a &= __float_as_int(u3.x) & __float_as_int(u3.y) & __float_as_int(u3.z) & __float_as_int(u3.w);
                a &= __float_as_int(u4.x) & __float_as_int(u4.y) & __float_as_int(u4.z) & __float_as_int(u4.w);
                a &= __float_as_int(u5.x) & __float_as_int(u5.y) & __float_as_int(u5.z) & __float_as_int(u5.w);
                a &= __float_as_int(u6.x) & __float_as_int(u6.y) & __float_as_int(u6.z) & __float_as_int(u6.w);
                a &= __float_as_int(u7.x) & __float_as_int(u7.y) & __float_as_int(u7.z) & __float_as_int(u7.w);
                fresh = (a < 0);                   // all sign bits set
            } else {
                int o = __float_as_int(u0.x) | __float_as_int(u0.y) | __float_as_int(u0.z) | __float_as_int(u0.w);
                o |= __float_as_int(u1.x) | __float_as_int(u1.y) | __float_as_int(u1.z) | __float_as_int(u1.w);
                o |= __float_as_int(u2.x) | __float_as_int(u2.y) | __float_as_int(u2.z) | __float_as_int(u2.w);
                o |= __float_as_int(u3.x) | __float_as_int(u3.y) | __float_as_int(u3.z) | __float_as_int(u3.w);
                o |= __float_as_int(u4.x) | __float_as_int(u4.y) | __float_as_int(u4.z) | __float_as_int(u4.w);
                o |= __float_as_int(u5.x) | __float_as_int(u5.y) | __float_as_int(u5.z) | __float_as_int(u5.w);
                o |= __float_as_int(u6.x) | __float_as_int(u6.y) | __float_as_int(u6.z) | __float_as_int(u6.w);
                o |= __float_as_int(u7.x) | __float_as_int(u7.y) | __float_as_int(u7.z) | __float_as_int(u7.w);
                fresh = (o >= 0);                  // all sign bits clear
            }
            if (__all(fresh)) break;
        }

        // ---- gmax = max |u_in| (identical in every wave -> consistent rescale)
        float m;
        m =           fmaxf(fmaxf(fabsf(u0.x), fabsf(u0.y)), fmaxf(fabsf(u0.z), fabsf(u0.w)));
        m = fmaxf(m,  fmaxf(fmaxf(fabsf(u1.x), fabsf(u1.y)), fmaxf(fabsf(u1.z), fabsf(u1.w))));
        m = fmaxf(m,  fmaxf(fmaxf(fabsf(u2.x), fabsf(u2.y)), fmaxf(fabsf(u2.z), fabsf(u2.w))));
        m = fmaxf(m,  fmaxf(fmaxf(fabsf(u3.x), fabsf(u3.y)), fmaxf(fabsf(u3.z), fabsf(u3.w))));
        m = fmaxf(m,  fmaxf(fmaxf(fabsf(u4.x), fabsf(u4.y)), fmaxf(fabsf(u4.z), fabsf(u4.w))));
        m = fmaxf(m,  fmaxf(fmaxf(fabsf(u5.x), fabsf(u5.y)), fmaxf(fabsf(u5.z), fabsf(u5.w))));
        m = fmaxf(m,  fmaxf(fmaxf(fabsf(u6.x), fabsf(u6.y)), fmaxf(fabsf(u6.z), fabsf(u6.w))));
        m = fmaxf(m,  fmaxf(fmaxf(fabsf(u7.x), fabsf(u7.y)), fmaxf(fabsf(u7.z), fabsf(u7.w))));
        #pragma unroll
        for (int d = 1; d < 64; d <<= 1) m = fmaxf(m, __shfl_xor(m, d, 64));

        // normalize (fold input sign) BEFORE f16 conversion: u_norm in [0,1]
        const float rn = (in_neg ? -1.0f : 1.0f) / m;
        h2f uh[16];
        uh[0]  = pk16(u0.x * rn, u0.y * rn);
        uh[1]  = pk16(u0.z * rn, u0.w * rn);
        uh[2]  = pk16(u1.x * rn, u1.y * rn);
        uh[3]  = pk16(u1.z * rn, u1.w * rn);
        uh[4]  = pk16(u2.x * rn, u2.y * rn);
        uh[5]  = pk16(u2.z * rn, u2.w * rn);
        uh[6]  = pk16(u3.x * rn, u3.y * rn);
        uh[7]  = pk16(u3.z * rn, u3.w * rn);
        uh[8]  = pk16(u4.x * rn, u4.y * rn);
        uh[9]  = pk16(u4.z * rn, u4.w * rn);
        uh[10] = pk16(u5.x * rn, u5.y * rn);
        uh[11] = pk16(u5.z * rn, u5.w * rn);
        uh[12] = pk16(u6.x * rn, u6.y * rn);
        uh[13] = pk16(u6.z * rn, u6.w * rn);
        uh[14] = pk16(u7.x * rn, u7.y * rn);
        uh[15] = pk16(u7.z * rn, u7.w * rn);

        // ---- GEMV via v_dot2_f32_f16: acc[r] = sum_j E[row_base+r][j] * u_norm[j]
        float acc[8];
        #pragma unroll
        for (int r = 0; r < 8; ++r) acc[r] = 0.0f;
        #pragma unroll
        for (int k = 0; k < 16; ++k) {
            #pragma unroll
            for (int r = 0; r < 8; ++r)
                acc[r] = __builtin_amdgcn_fdot2(e2[r][k], uh[k], acc[r], false);
        }

        // ---- multi-row butterfly: 8 rows x 64 lanes -> row q(lane), lanes 0..7
        #pragma unroll
        for (int r = 0; r < 4; ++r) {
            float send = (lane & 1) ? acc[r] : acc[r + 4];
            float recv = __shfl_xor(send, 1, 64);
            float keep = (lane & 1) ? acc[r + 4] : acc[r];
            acc[r] = keep + recv;
        }
        #pragma unroll
        for (int r = 0; r < 2; ++r) {
            float send = (lane & 2) ? acc[r] : acc[r + 2];
            float recv = __shfl_xor(send, 2, 64);
            float keep = (lane & 2) ? acc[r + 2] : acc[r];
            acc[r] = keep + recv;
        }
        {
            float send = (lane & 4) ? acc[0] : acc[1];
            float recv = __shfl_xor(send, 4, 64);
            float keep = (lane & 4) ? acc[1] : acc[0];
            acc[0] = keep + recv;
        }
        acc[0] += __shfl_xor(acc[0], 8, 64);
        acc[0] += __shfl_xor(acc[0], 16, 64);
        acc[0] += __shfl_xor(acc[0], 32, 64);

        // log-scale accumulation for kept steps (m==1.0 at t==0 -> adds 0)
        if ((s + 1) > s_keep) Chat += __logf(m);

        if (lane < 8) {
            float ut = acc[0] * __expf(hv);        // true (positive) value
            st_coh(&u_out[grow], out_neg ? -ut : ut);
            if (c > 0 && (s + 1) == s_keep) st_coh(&usave[c * TSZ + grow], ut);
            if ((s + 1) == s_end)           st_coh(&ufin[c * TSZ + grow], ut);
        }
    }

    // ---- completion: ack all my stores at L3, then per-wave post
    if (b == 0 && wv == 0 && lane == 0) st_coh(&cbuf[c], Chat);
    asm volatile("s_waitcnt vmcnt(0)" ::: "memory");
    if (lane == 0)
        __hip_atomic_store(&posts[blk * 4 + wv], 1,
                           __ATOMIC_RELAXED, __HIP_MEMORY_SCOPE_AGENT);

    // ---- finisher: chunk 0 / block 0 / wave 0 stitches chunks, writes scalar
    if (c == 0 && b == 0 && wv == 0) {
        int ok;
        do {
            __builtin_amdgcn_s_sleep(1);
            ok = 1;
            #pragma unroll
            for (int i = 0; i < 16; ++i) {
                int v = __hip_atomic_load(&posts[lane + 64 * i],
                                          __ATOMIC_RELAXED, __HIP_MEMORY_SCOPE_AGENT);
                ok &= (v == 1);
            }
        } while (!__all(ok));

        // stitch: match log(sum u) at chunk boundaries
        float O = 0.0f;
        for (int cc = 1; cc < NCH; ++cc) {
            float sa = 0.0f, sb = 0.0f;
            for (int j = 4 * lane; j < TSZ; j += 256) {
                v4f a4 = ld_coh4(&ufin[(cc - 1) * TSZ + j]);
                v4f b4 = ld_coh4(&usave[cc * TSZ + j]);
                sa += a4.x + a4.y + a4.z + a4.w;
                sb += b4.x + b4.y + b4.z + b4.w;
            }
            #pragma unroll
            for (int d = 1; d < 64; d <<= 1) {
                sa += __shfl_xor(sa, d, 64);
                sb += __shfl_xor(sb, d, 64);
            }
            v4f c4 = ld_coh4(&cbuf[0]);
            float cv = (cc - 1 == 0) ? c4.x : (cc - 1 == 1) ? c4.y : c4.z;
            O += cv + __logf(sa) - __logf(sb);
        }
        // terminal: O + C_last + log(sum_j exp(T[END,j]) u_j)
        float se = 0.0f;
        for (int j = 4 * lane; j < TSZ; j += 256) {
            const float4 t4 = *(const float4*)(tr + (size_t)END_I * TSZ + j);
            v4f uf = ld_coh4(&ufin[(NCH - 1) * TSZ + j]);
            se += __expf(t4.x) * uf.x + __expf(t4.y) * uf.y +
                  __expf(t4.z) * uf.z + __expf(t4.w) * uf.w;
        }
        #pragma unroll
        for (int d = 1; d < 64; d <<= 1) se += __shfl_xor(se, d, 64);

        v4f c4 = ld_coh4(&cbuf[0]);
        float ans = O + c4.w + __logf(se);
        if (lane == 0) out[0] = ans;
    }
}

extern "C" void kernel_launch(void* const* d_in, const int* in_sizes, int n_in,
                              void* d_out, int out_size, void* d_ws, size_t ws_size,
                              hipStream_t stream) {
    const float* h  = (const float*)d_in[0];   // [8192, 2048] fp32 emissions
    const float* tr = (const float*)d_in[1];   // [2048, 2048] fp32 transitions
    (void)in_sizes; (void)n_in; (void)out_size; (void)ws_size;
    crf_chain<<<dim3(NCH * GBLK), dim3(256), 0, stream>>>(h, tr, (float*)d_out, (float*)d_ws);
}

// Round 6
// 2689.041 us; speedup vs baseline: 21.2821x; 1.7483x over previous
//
#include <hip/hip_runtime.h>

// CRF forward chain on MI355X — linearized: u' = (1/g) diag(exp(h_s)) E u,
// E = exp(transitions) packed as f16 pairs (register-resident, 128 VGPR/lane).
// answer = C + log(sum_j exp(T[END,j]) u_j).
// R6: 8 chunks (Perron-Frobenius, BURN-step burn-in) x 32 blocks x 512 threads
// (8 waves, 64 rows/block). DATAFLOW SYNC as R5 (sign-tagged u, poll IS the
// load), but only WAVE 0 of each block polls; it normalizes + packs to f16 and
// broadcasts via LDS (4KB); other waves pick up after one __syncthreads.
// Single barrier per step; LDS overwrite is race-free by the dataflow chain
// (own block's stores of step t+1 imply its waves finished reading LDS(t)).
//
// ws floats: u_bufs[8][2][2048] @0, usave[8][2048] @32768, ufin[8][2048] @49152,
// cbuf[8] @65536 ; posts int[2048] @byte 262208.

#define TSZ   2048
#define NCH   8
#define GBLK  32
#define NW    8
#define CH_LEN 1024
#define BURN  24
#define START_I 0
#define END_I   1

typedef float v4f __attribute__((ext_vector_type(4)));
typedef _Float16 h2f __attribute__((ext_vector_type(2)));

__device__ __forceinline__ h2f pk16(float a, float b) {
    return __builtin_bit_cast(h2f, __builtin_amdgcn_cvt_pkrtz(a, b));
}
__device__ __forceinline__ void st_coh(float* p, float v) {
    asm volatile("global_store_dword %0, %1, off sc0 sc1"
                 :: "v"(p), "v"(v) : "memory");
}
__device__ __forceinline__ float ld_coh1(const float* p) {
    float r;
    asm volatile("global_load_dword %0, %1, off sc0 sc1\n\ts_waitcnt vmcnt(0)"
                 : "=&v"(r) : "v"(p) : "memory");
    return r;
}
__device__ __forceinline__ v4f ld_coh4(const float* p) {
    v4f r;
    asm volatile("global_load_dwordx4 %0, %1, off sc0 sc1\n\ts_waitcnt vmcnt(0)"
                 : "=&v"(r) : "v"(p) : "memory");
    return r;
}

__global__ __launch_bounds__(512, 2)
void crf_chain(const float* __restrict__ h, const float* __restrict__ tr,
               float* __restrict__ out, float* __restrict__ ws)
{
    const int tid  = threadIdx.x;
    const int lane = tid & 63;
    const int wv   = tid >> 6;          // 0..7
    const int blk  = blockIdx.x;
    const int c    = blk >> 5;          // chunk id 0..7
    const int b    = blk & (GBLK - 1);  // block within chunk 0..31
    const int row_base = b * 64 + wv * 8;

    float* u_bufs = ws;                               // [NCH][2][TSZ]
    float* usave  = ws + NCH * 2 * TSZ;               // [NCH][TSZ]
    float* ufin   = usave + NCH * TSZ;                // [NCH][TSZ]
    float* cbuf   = ufin + NCH * TSZ;                 // [NCH]
    int*   posts  = (int*)((char*)ws + 262208);       // [2048] per-wave completion

    // ---- one-time: E fragment, f16-pair packed. Lane covers cols 4*lane + 256*k + m.
    h2f e2[8][16];
    #pragma unroll
    for (int r = 0; r < 8; ++r) {
        const float* trow = tr + (size_t)(row_base + r) * TSZ + 4 * lane;
        #pragma unroll
        for (int k = 0; k < 8; ++k) {
            float4 t4 = *(const float4*)(trow + 256 * k);
            e2[r][2 * k]     = pk16(__expf(t4.x), __expf(t4.y));
            e2[r][2 * k + 1] = pk16(__expf(t4.z), __expf(t4.w));
        }
    }

    const int s_keep  = c * CH_LEN;
    const int s_begin = (c == 0) ? 0 : (s_keep - BURN);
    const int s_end   = s_keep + CH_LEN;
    const int T_iter  = s_end - s_begin;

    const int q    = ((lane & 1) << 2) | (lane & 2) | ((lane >> 2) & 1);
    const int grow = row_base + q;

    __shared__ unsigned long long uh_sh[512];   // 2048 normalized f16 values

    // ---- init: u^0 into buf parity 0, POSITIVE tag (poison 0xAA.. is negative)
    if (tid < 64) {
        int row = b * 64 + tid;
        float v = (c == 0) ? ((row == START_I) ? 1.0f : 0.0f) : 1.0f;
        st_coh(&u_bufs[(c * 2 + 0) * TSZ + row], v);
    }

    float Chat = 0.0f;

    for (int t = 0; t < T_iter; ++t) {
        const int s = s_begin + t;
        float* u_out = u_bufs + (c * 2 + ((t + 1) & 1)) * TSZ;
        const int out_neg = ((t + 1) >> 1) & 1;    // tag we write

        // prefetch emission (plain cached load) to overlap the wait
        float hv = 0.0f;
        if (lane < 8) hv = h[(size_t)s * TSZ + grow];

        if (wv == 0) {
            const float* u_in = u_bufs + (c * 2 + (t & 1)) * TSZ;
            const int in_neg  = (t >> 1) & 1;      // expected tag of u_in

            // ---- poll-by-load: re-load until every value carries the expected sign
            v4f u0, u1, u2, u3, u4, u5, u6, u7;
            const float* pa = u_in + 4 * lane;       // k=0..3
            const float* pb = pa + 1024;             // k=4..7
            for (;;) {
                asm volatile(
                    "global_load_dwordx4 %0, %8, off sc0 sc1\n\t"
                    "global_load_dwordx4 %1, %8, off offset:1024 sc0 sc1\n\t"
                    "global_load_dwordx4 %2, %8, off offset:2048 sc0 sc1\n\t"
                    "global_load_dwordx4 %3, %8, off offset:3072 sc0 sc1\n\t"
                    "global_load_dwordx4 %4, %9, off sc0 sc1\n\t"
                    "global_load_dwordx4 %5, %9, off offset:1024 sc0 sc1\n\t"
                    "global_load_dwordx4 %6, %9, off offset:2048 sc0 sc1\n\t"
                    "global_load_dwordx4 %7, %9, off offset:3072 sc0 sc1\n\t"
                    "s_waitcnt vmcnt(0)"
                    : "=&v"(u0), "=&v"(u1), "=&v"(u2), "=&v"(u3),
                      "=&v"(u4), "=&v"(u5), "=&v"(u6), "=&v"(u7)
                    : "v"(pa), "v"(pb)
                    : "memory");
                bool fresh;
                if (in_neg) {
                    int a = __float_as_int(u0.x) & __float_as_int(u0.y) & __float_as_int(u0.z) & __float_as_int(u0.w);
                    a &= __float_as_int(u1.x) & __float_as_int(u1.y) & __float_as_int(u1.z) & __float_as_int(u1.w);
                    a &= __float_as_int(u2.x) & __float_as_int(u2.y) & __float_as_int(u2.z) & __float_as_int(u2.w);
                    a &= __float_as_int(u3.x) & __float_as_int(u3.y) & __float_as_int(u3.z) & __float_as_int(u3.w);
                    a &= __float_as_int(u4.x) & __float_as_int(u4.y) & __float_as_int(u4.z) & __float_as_int(u4.w);
                    a &= __float_as_int(u5.x) & __float_as_int(u5.y) & __float_as_int(u5.z) & __float_as_int(u5.w);
                    a &= __float_as_int(u6.x) & __float_as_int(u6.y) & __float_as_int(u6.z) & __float_as_int(u6.w);
                    a &= __float_as_int(u7.x) & __float_as_int(u7.y) & __float_as_int(u7.z) & __float_as_int(u7.w);
                    fresh = (a < 0);                   // all sign bits set
                } else {
                    int o = __float_as_int(u0.x) | __float_as_int(u0.y) | __float_as_int(u0.z) | __float_as_int(u0.w);
                    o |= __float_as_int(u1.x) | __float_as_int(u1.y) | __float_as_int(u1.z) | __float_as_int(u1.w);
                    o |= __float_as_int(u2.x) | __float_as_int(u2.y) | __float_as_int(u2.z) | __float_as_int(u2.w);
                    o |= __float_as_int(u3.x) | __float_as_int(u3.y) | __float_as_int(u3.z) | __float_as_int(u3.w);
                    o |= __float_as_int(u4.x) | __float_as_int(u4.y) | __float_as_int(u4.z) | __float_as_int(u4.w);
                    o |= __float_as_int(u5.x) | __float_as_int(u5.y) | __float_as_int(u5.z) | __float_as_int(u5.w);
                    o |= __float_as_int(u6.x) | __float_as_int(u6.y) | __float_as_int(u6.z) | __float_as_int(u6.w);
                    o |= __float_as_int(u7.x) | __float_as_int(u7.y) | __float_as_int(u7.z) | __float_as_int(u7.w);
                    fresh = (o >= 0);                  // all sign bits clear
                }
                if (__all(fresh)) break;
            }

            // ---- gmax = max |u_in| (bitwise-identical in every polling wave)
            float m;
            m =          fmaxf(fmaxf(fabsf(u0.x), fabsf(u0.y)), fmaxf(fabsf(u0.z), fabsf(u0.w)));
            m = fmaxf(m, fmaxf(fmaxf(fabsf(u1.x), fabsf(u1.y)), fmaxf(fabsf(u1.z), fabsf(u1.w))));
            m = fmaxf(m, fmaxf(fmaxf(fabsf(u2.x), fabsf(u2.y)), fmaxf(fabsf(u2.z), fabsf(u2.w))));
            m = fmaxf(m, fmaxf(fmaxf(fabsf(u3.x), fabsf(u3.y)), fmaxf(fabsf(u3.z), fabsf(u3.w))));
            m = fmaxf(m, fmaxf(fmaxf(fabsf(u4.x), fabsf(u4.y)), fmaxf(fabsf(u4.z), fabsf(u4.w))));
            m = fmaxf(m, fmaxf(fmaxf(fabsf(u5.x), fabsf(u5.y)), fmaxf(fabsf(u5.z), fabsf(u5.w))));
            m = fmaxf(m, fmaxf(fmaxf(fabsf(u6.x), fabsf(u6.y)), fmaxf(fabsf(u6.z), fabsf(u6.w))));
            m = fmaxf(m, fmaxf(fmaxf(fabsf(u7.x), fabsf(u7.y)), fmaxf(fabsf(u7.z), fabsf(u7.w))));
            #pragma unroll
            for (int d = 1; d < 64; d <<= 1) m = fmaxf(m, __shfl_xor(m, d, 64));

            // normalize (fold input sign), pack to f16, broadcast via LDS
            const float rn = (in_neg ? -1.0f : 1.0f) / m;
            h2f uh[16];
            uh[0]  = pk16(u0.x * rn, u0.y * rn);  uh[1]  = pk16(u0.z * rn, u0.w * rn);
            uh[2]  = pk16(u1.x * rn, u1.y * rn);  uh[3]  = pk16(u1.z * rn, u1.w * rn);
            uh[4]  = pk16(u2.x * rn, u2.y * rn);  uh[5]  = pk16(u2.z * rn, u2.w * rn);
            uh[6]  = pk16(u3.x * rn, u3.y * rn);  uh[7]  = pk16(u3.z * rn, u3.w * rn);
            uh[8]  = pk16(u4.x * rn, u4.y * rn);  uh[9]  = pk16(u4.z * rn, u4.w * rn);
            uh[10] = pk16(u5.x * rn, u5.y * rn);  uh[11] = pk16(u5.z * rn, u5.w * rn);
            uh[12] = pk16(u6.x * rn, u6.y * rn);  uh[13] = pk16(u6.z * rn, u6.w * rn);
            uh[14] = pk16(u7.x * rn, u7.y * rn);  uh[15] = pk16(u7.z * rn, u7.w * rn);
            #pragma unroll
            for (int k = 0; k < 8; ++k) {
                unsigned long long qw =
                    ((unsigned long long)__builtin_bit_cast(unsigned, uh[2 * k + 1]) << 32) |
                    (unsigned long long)__builtin_bit_cast(unsigned, uh[2 * k]);
                uh_sh[lane + 64 * k] = qw;
            }

            // log-scale accumulation for kept steps (m==1.0 at t==0 -> adds 0)
            if ((s + 1) > s_keep) Chat += __logf(m);
        }

        __syncthreads();   // LDS(t) ready; overwrite at t+1 is dataflow-safe

        // ---- all waves: unpack normalized u from LDS
        h2f uh[16];
        #pragma unroll
        for (int k = 0; k < 8; ++k) {
            unsigned long long qw = uh_sh[lane + 64 * k];
            uh[2 * k]     = __builtin_bit_cast(h2f, (unsigned)qw);
            uh[2 * k + 1] = __builtin_bit_cast(h2f, (unsigned)(qw >> 32));
        }

        // ---- GEMV via v_dot2_f32_f16: acc[r] = sum_j E[row_base+r][j] * u_norm[j]
        float acc[8];
        #pragma unroll
        for (int r = 0; r < 8; ++r) acc[r] = 0.0f;
        #pragma unroll
        for (int k = 0; k < 16; ++k) {
            #pragma unroll
            for (int r = 0; r < 8; ++r)
                acc[r] = __builtin_amdgcn_fdot2(e2[r][k], uh[k], acc[r], false);
        }

        // ---- multi-row butterfly: 8 rows x 64 lanes -> row q(lane), lanes 0..7
        #pragma unroll
        for (int r = 0; r < 4; ++r) {
            float send = (lane & 1) ? acc[r] : acc[r + 4];
            float recv = __shfl_xor(send, 1, 64);
            float keep = (lane & 1) ? acc[r + 4] : acc[r];
            acc[r] = keep + recv;
        }
        #pragma unroll
        for (int r = 0; r < 2; ++r) {
            float send = (lane & 2) ? acc[r] : acc[r + 2];
            float recv = __shfl_xor(send, 2, 64);
            float keep = (lane & 2) ? acc[r + 2] : acc[r];
            acc[r] = keep + recv;
        }
        {
            float send = (lane & 4) ? acc[0] : acc[1];
            float recv = __shfl_xor(send, 4, 64);
            float keep = (lane & 4) ? acc[1] : acc[0];
            acc[0] = keep + recv;
        }
        acc[0] += __shfl_xor(acc[0], 8, 64);
        acc[0] += __shfl_xor(acc[0], 16, 64);
        acc[0] += __shfl_xor(acc[0], 32, 64);

        if (lane < 8) {
            float ut = acc[0] * __expf(hv);        // true (positive) value
            st_coh(&u_out[grow], out_neg ? -ut : ut);
            if (c > 0 && (s + 1) == s_keep) st_coh(&usave[c * TSZ + grow], ut);
            if ((s + 1) == s_end)           st_coh(&ufin[c * TSZ + grow], ut);
        }
    }

    // ---- completion: ack all my stores at L3, then per-wave post
    if (b == 0 && wv == 0 && lane == 0) st_coh(&cbuf[c], Chat);
    asm volatile("s_waitcnt vmcnt(0)" ::: "memory");
    if (lane == 0)
        __hip_atomic_store(&posts[blk * NW + wv], 1,
                           __ATOMIC_RELAXED, __HIP_MEMORY_SCOPE_AGENT);

    // ---- finisher: chunk 0 / block 0 / wave 0 stitches chunks, writes scalar
    if (c == 0 && b == 0 && wv == 0) {
        int ok;
        do {
            __builtin_amdgcn_s_sleep(1);
            ok = 1;
            #pragma unroll
            for (int i = 0; i < 32; ++i) {
                int v = __hip_atomic_load(&posts[lane + 64 * i],
                                          __ATOMIC_RELAXED, __HIP_MEMORY_SCOPE_AGENT);
                ok &= (v == 1);
            }
        } while (!__all(ok));

        // stitch: match log(sum u) at chunk boundaries
        float O = 0.0f;
        for (int cc = 1; cc < NCH; ++cc) {
            float sa = 0.0f, sb = 0.0f;
            for (int j = 4 * lane; j < TSZ; j += 256) {
                v4f a4 = ld_coh4(&ufin[(cc - 1) * TSZ + j]);
                v4f b4 = ld_coh4(&usave[cc * TSZ + j]);
                sa += a4.x + a4.y + a4.z + a4.w;
                sb += b4.x + b4.y + b4.z + b4.w;
            }
            #pragma unroll
            for (int d = 1; d < 64; d <<= 1) {
                sa += __shfl_xor(sa, d, 64);
                sb += __shfl_xor(sb, d, 64);
            }
            O += ld_coh1(&cbuf[cc - 1]) + __logf(sa) - __logf(sb);
        }
        // terminal: O + C_last + log(sum_j exp(T[END,j]) u_j)
        float se = 0.0f;
        for (int j = 4 * lane; j < TSZ; j += 256) {
            const float4 t4 = *(const float4*)(tr + (size_t)END_I * TSZ + j);
            v4f uf = ld_coh4(&ufin[(NCH - 1) * TSZ + j]);
            se += __expf(t4.x) * uf.x + __expf(t4.y) * uf.y +
                  __expf(t4.z) * uf.z + __expf(t4.w) * uf.w;
        }
        #pragma unroll
        for (int d = 1; d < 64; d <<= 1) se += __shfl_xor(se, d, 64);

        float ans = O + ld_coh1(&cbuf[NCH - 1]) + __logf(se);
        if (lane == 0) out[0] = ans;
    }
}

extern "C" void kernel_launch(void* const* d_in, const int* in_sizes, int n_in,
                              void* d_out, int out_size, void* d_ws, size_t ws_size,
                              hipStream_t stream) {
    const float* h  = (const float*)d_in[0];   // [8192, 2048] fp32 emissions
    const float* tr = (const float*)d_in[1];   // [2048, 2048] fp32 transitions
    (void)in_sizes; (void)n_in; (void)out_size; (void)ws_size;
    crf_chain<<<dim3(NCH * GBLK), dim3(512), 0, stream>>>(h, tr, (float*)d_out, (float*)d_ws);
}